// Round 3
// baseline (652.376 us; speedup 1.0000x reference)
//
#include <hip/hip_runtime.h>
#include <hip/hip_fp16.h>
#include <hip/hip_bf16.h>
#include <stdint.h>

// ---------------------------------------------------------------------------
// ResidualVQ: x (64,512,256) f32, codebooks (6,1024,512) f32
// outputs: quantized_out (64,512,256), indices (64,256,6) as f32,
//          mean_loss, mean_perplexity   -> d_out flat f32, 8486914 elems
//
// R2 -> R3: dist matrix (fp16, 67 MB/stage round-trip) eliminated. GEMM
// epilogue reduces each (row, 64-col group) to top-2 (dist,col) candidates
// -> cand table 16384 x 16 x float4 (4 MB). refine reads 128 B/row of
// candidates (instead of 2 KB fp16 scan with serialized ballots), exact-fp32
// rescans entries within MARGIN of the approx min, updates residual.
// minkey atomics removed; refine vectorized to float4/16B-per-lane layout.
// ---------------------------------------------------------------------------

#define NTROWS 16384
#define DDIM   512
#define CCODES 1024
#define QSTAGE 6

// ws layout (bytes)
#define OFF_R      ((size_t)0)           // fp32 residual  NT*D*4   = 33554432
#define OFF_RBF    ((size_t)33554432)    // bf16 residual  NT*D*2   = 16777216
#define OFF_CBBF   ((size_t)50331648)    // bf16 codebooks 6*1024*512*2 = 6291456
#define OFF_CAND   ((size_t)56623104)    // f32x4 cand     NT*16*16  = 4194304
#define OFF_CBSQ   ((size_t)60817408)    // f32 |c|^2, 6*1024*4
#define OFF_HIST   ((size_t)60841984)    // u32 hist, 6*1024*4
#define OFF_LOSS   ((size_t)60866560)    // f32 loss bins, 6*256*4
#define WS_END     ((size_t)60872704)

#define OUT_IDX_OFF  ((size_t)8388608)
#define OUT_SCAL_OFF ((size_t)8486912)

typedef __attribute__((ext_vector_type(8))) short short8;
typedef __attribute__((ext_vector_type(8))) unsigned short ushort8v;
typedef __attribute__((ext_vector_type(4))) float f32x4;

__device__ __forceinline__ unsigned short f2bf(float f) {
    uint32_t u = __float_as_uint(f);
    uint32_t r = (u + 0x7fffu + ((u >> 16) & 1u)) >> 16;   // RNE
    return (unsigned short)r;
}
__device__ __forceinline__ float wave_sum(float v) {
    for (int m = 32; m; m >>= 1) v += __shfl_xor(v, m, 64);
    return v;
}
__device__ __forceinline__ float wave_min(float v) {
    for (int m = 32; m; m >>= 1) v = fminf(v, __shfl_xor(v, m, 64));
    return v;
}
__device__ __forceinline__ void async_load16(const void* g, void* l) {
    __builtin_amdgcn_global_load_lds(
        (__attribute__((address_space(1))) void*)(void*)g,
        (__attribute__((address_space(3))) void*)l, 16, 0, 0);
}

// --------------------------------------------------------------------------
// prep_cb: bf16 codebooks + |c|^2 ; also zero hist/loss bins (block 0)
// grid 1536 x 256 (wave per code row)
// --------------------------------------------------------------------------
__global__ __launch_bounds__(256) void prep_cb_kernel(
    const float* __restrict__ cb, unsigned short* __restrict__ cbbf,
    float* __restrict__ cbsq, unsigned int* __restrict__ hist,
    float* __restrict__ loss_bins)
{
    const int wave = threadIdx.x >> 6, lane = threadIdx.x & 63;
    const int row = blockIdx.x * 4 + wave;            // 0..6143
    const float* p = cb + (size_t)row * DDIM;
    unsigned short* pb = cbbf + (size_t)row * DDIM;
    float s = 0.f;
#pragma unroll
    for (int t = 0; t < 8; ++t) {
        float v = p[lane + 64 * t];
        pb[lane + 64 * t] = f2bf(v);
        s += v * v;
    }
    s = wave_sum(s);
    if (lane == 0) cbsq[row] = s;
    if (blockIdx.x == 0) {
        for (int i = threadIdx.x; i < QSTAGE * CCODES; i += 256) hist[i] = 0u;
        for (int i = threadIdx.x; i < QSTAGE * 256; i += 256) loss_bins[i] = 0.f;
    }
}

// --------------------------------------------------------------------------
// prep_x: transpose x (N,D,T) -> r (NT,D) fp32+bf16
// grid (16,8,64) block (32,8)
// --------------------------------------------------------------------------
__global__ void prep_x_kernel(const float* __restrict__ x, float* __restrict__ r,
                              unsigned short* __restrict__ rbf)
{
    __shared__ float tile[32][33];
    const int d0 = blockIdx.x * 32, t0 = blockIdx.y * 32, n = blockIdx.z;
    const int tx = threadIdx.x, ty = threadIdx.y;
    const float* xp = x + (size_t)n * (DDIM * 256);
#pragma unroll
    for (int s = 0; s < 4; ++s) {
        int dd = ty + s * 8;
        tile[dd][tx] = xp[(size_t)(d0 + dd) * 256 + t0 + tx];
    }
    __syncthreads();
#pragma unroll
    for (int s = 0; s < 4; ++s) {
        int tt = ty + s * 8;
        float v = tile[tx][tt];
        size_t off = (size_t)(n * 256 + t0 + tt) * DDIM + d0 + tx;
        r[off] = v;
        rbf[off] = f2bf(v);
    }
}

// --------------------------------------------------------------------------
// GEMM: dist'[row][col] = cbsq[col] - 2 * dot(r_row, c_col), bf16 MFMA.
// Epilogue: top-2 (dist, col) per (row, 64-col wave-group) -> cand table.
// grid (8,128) x 256
// --------------------------------------------------------------------------
__global__ __launch_bounds__(256) void gemm_dist_kernel(
    const unsigned short* __restrict__ Abf,   // NT x 512 bf16
    const unsigned short* __restrict__ Bbf,   // 1024 x 512 bf16 (stage slice)
    const float* __restrict__ cbsq,           // 1024 (stage slice)
    float* __restrict__ cand)                 // NT x 16 x float4(d1,c1,d2,c2)
{
    __shared__ __align__(16) unsigned short lA[128 * 32];
    __shared__ __align__(16) unsigned short lB[128 * 32];
    const int tid = threadIdx.x;
    const int wave = tid >> 6, lane = tid & 63;
    const int quad = lane >> 4, l15 = lane & 15;
    const int tm = blockIdx.y, tn = blockIdx.x;
    const int wm = wave & 1, wn = wave >> 1;

    f32x4 acc[4][4];
#pragma unroll
    for (int i = 0; i < 4; ++i)
#pragma unroll
        for (int j = 0; j < 4; ++j) acc[i][j] = (f32x4){0.f, 0.f, 0.f, 0.f};

    // staging: wave w loads rows [w*16 + lane>>2] and +64, chunk = lane&3 (16B)
    const int srow = wave * 16 + (lane >> 2);
    const int schunk = lane & 3;
    const unsigned short* gA0 = Abf + (size_t)(tm * 128 + srow) * DDIM + schunk * 8;
    const unsigned short* gA1 = gA0 + 64 * DDIM;
    const unsigned short* gB0 = Bbf + (size_t)(tn * 128 + srow) * DDIM + schunk * 8;
    const unsigned short* gB1 = gB0 + 64 * DDIM;
    unsigned short* sA0 = &lA[srow * 32 + schunk * 8];
    unsigned short* sA1 = &lA[(64 + srow) * 32 + schunk * 8];
    unsigned short* sB0 = &lB[srow * 32 + schunk * 8];
    unsigned short* sB1 = &lB[(64 + srow) * 32 + schunk * 8];

    for (int kt = 0; kt < DDIM / 32; ++kt) {
        async_load16(gA0, sA0); async_load16(gA1, sA1);
        async_load16(gB0, sB0); async_load16(gB1, sB1);
        gA0 += 32; gA1 += 32; gB0 += 32; gB1 += 32;
        __syncthreads();   // drains vmcnt before LDS reads
        short8 af[4], bfr[4];
#pragma unroll
        for (int i = 0; i < 4; ++i)
            af[i] = *(const short8*)&lA[(wm * 64 + i * 16 + l15) * 32 + quad * 8];
#pragma unroll
        for (int j = 0; j < 4; ++j)
            bfr[j] = *(const short8*)&lB[(wn * 64 + j * 16 + l15) * 32 + quad * 8];
#pragma unroll
        for (int i = 0; i < 4; ++i)
#pragma unroll
            for (int j = 0; j < 4; ++j)
                acc[i][j] = __builtin_amdgcn_mfma_f32_16x16x32_bf16(
                    af[i], bfr[j], acc[i][j], 0, 0, 0);
        __syncthreads();   // before next tile overwrites LDS
    }

    // epilogue: C/D layout col=lane&15, row=quad*4+reg (m89-verified).
    // Per row, top-2 over this wave's 64 cols via intra-quad shfl merge.
    const int rowbase = tm * 128 + wm * 64 + quad * 4;
    const int colbase = tn * 128 + wn * 64 + l15;
    const int g = tn * 2 + wn;                 // 64-col group index, 0..15
    float cbs[4];
#pragma unroll
    for (int j = 0; j < 4; ++j) cbs[j] = cbsq[colbase + j * 16];
#pragma unroll
    for (int i = 0; i < 4; ++i) {
#pragma unroll
        for (int reg = 0; reg < 4; ++reg) {
            // lane-local top-2 over j (cols ascending => first-index kept on tie)
            float d1 = 1e30f, c1 = 0.f, d2 = 1e30f, c2 = 0.f;
#pragma unroll
            for (int j = 0; j < 4; ++j) {
                float dv = cbs[j] - 2.0f * acc[i][j][reg];
                float cv = (float)(colbase + j * 16);
                if (dv < d1) { d2 = d1; c2 = c1; d1 = dv; c1 = cv; }
                else if (dv < d2) { d2 = dv; c2 = cv; }
            }
            // merge across the 16 lanes of this quad (xor masks stay in-quad)
#pragma unroll
            for (int m = 1; m < 16; m <<= 1) {
                float e1 = __shfl_xor(d1, m, 64), f1 = __shfl_xor(c1, m, 64);
                float e2 = __shfl_xor(d2, m, 64), f2 = __shfl_xor(c2, m, 64);
                bool sw = (e1 < d1) || (e1 == d1 && f1 < c1);
                if (sw) { float t;
                    t = d1; d1 = e1; e1 = t;
                    t = c1; c1 = f1; f1 = t; }
                bool p  = (d2 < e2) || (d2 == e2 && c2 < f2);
                float m2 = p ? d2 : e2, mc = p ? c2 : f2;
                bool q2 = (e1 < m2) || (e1 == m2 && f1 < mc);
                d2 = q2 ? e1 : m2; c2 = q2 ? f1 : mc;
            }
            if (l15 == 0) {
                const int row = rowbase + i * 16 + reg;
                float4 v = make_float4(d1, c1, d2, c2);
                *(float4*)&cand[((size_t)row * 16 + g) * 4] = v;
            }
        }
    }
}

// --------------------------------------------------------------------------
// refine+update: read 16 candidate pairs/row, exact fp32 recompute for all
// entries within MARGIN of approx min; r -= cb[best]; write fp32+bf16;
// loss += best (256-bin atomics); hist; index out.
// grid 4096 x 256 (wave per row, lane owns cols lane*8..lane*8+7)
// --------------------------------------------------------------------------
#define MARGIN 8.0f
__global__ __launch_bounds__(256) void refine_kernel(
    float* __restrict__ r, unsigned short* __restrict__ rbf,
    const float* __restrict__ cbq, const float* __restrict__ cbsqq,
    const float* __restrict__ cand,
    float* __restrict__ out_idx, unsigned int* __restrict__ histq,
    float* __restrict__ loss_bins, int q, int write_bf)
{
    const int wave = threadIdx.x >> 6, lane = threadIdx.x & 63;
    const int nt = blockIdx.x * 4 + wave;

    const float4* r4 = (const float4*)(r + (size_t)nt * DDIM);
    float4 ra = r4[lane * 2], rb = r4[lane * 2 + 1];
    float s = ra.x * ra.x + ra.y * ra.y + ra.z * ra.z + ra.w * ra.w
            + rb.x * rb.x + rb.y * rb.y + rb.z * rb.z + rb.w * rb.w;
    const float sumx = wave_sum(s);

    float4 cv = make_float4(1e30f, 0.f, 1e30f, 0.f);
    if (lane < 16) cv = *(const float4*)&cand[((size_t)nt * 16 + lane) * 4];
    const float dmin = wave_min(cv.x);
    const float thr = dmin + MARGIN;

    unsigned long long mask1 = __ballot(lane < 16 && cv.x <= thr);
    unsigned long long mask2 = __ballot(lane < 16 && cv.z <= thr);

    float best = 1e30f;
    int bestc = CCODES;
    for (int pass = 0; pass < 2; ++pass) {
        unsigned long long mask = pass ? mask2 : mask1;
        while (mask) {
            const int src = __ffsll(mask) - 1;
            mask &= mask - 1;
            const float cf = __shfl(pass ? cv.w : cv.y, src, 64);
            const int cc = (int)cf;
            const float4* crow = (const float4*)(cbq + (size_t)cc * DDIM);
            float4 ca = crow[lane * 2], cb2 = crow[lane * 2 + 1];
            float dot = ra.x * ca.x + ra.y * ca.y + ra.z * ca.z + ra.w * ca.w
                      + rb.x * cb2.x + rb.y * cb2.y + rb.z * cb2.z + rb.w * cb2.w;
            dot = wave_sum(dot);
            const float de = (sumx - 2.0f * dot) + cbsqq[cc];
            if (de < best || (de == best && cc < bestc)) { best = de; bestc = cc; }
        }
    }

    // merged residual update: bestc/best are wave-uniform
    const float4* cbest = (const float4*)(cbq + (size_t)bestc * DDIM);
    float4 ba = cbest[lane * 2], bb = cbest[lane * 2 + 1];
    float4 na = make_float4(ra.x - ba.x, ra.y - ba.y, ra.z - ba.z, ra.w - ba.w);
    float4 nb = make_float4(rb.x - bb.x, rb.y - bb.y, rb.z - bb.z, rb.w - bb.w);
    float4* rw = (float4*)(r + (size_t)nt * DDIM);
    rw[lane * 2] = na; rw[lane * 2 + 1] = nb;
    if (write_bf) {
        ushort8v pk;
        pk[0] = f2bf(na.x); pk[1] = f2bf(na.y); pk[2] = f2bf(na.z); pk[3] = f2bf(na.w);
        pk[4] = f2bf(nb.x); pk[5] = f2bf(nb.y); pk[6] = f2bf(nb.z); pk[7] = f2bf(nb.w);
        *(ushort8v*)(rbf + (size_t)nt * DDIM + lane * 8) = pk;
    }

    if (lane == 0) {
        out_idx[(size_t)nt * QSTAGE + q] = (float)bestc;
        atomicAdd(&histq[bestc], 1u);
        atomicAdd(&loss_bins[q * 256 + (blockIdx.x & 255)], best);
    }
}

// --------------------------------------------------------------------------
// final: out = x - r_final, transposed back to (N,D,T)
// grid (16,8,64) block (32,8)
// --------------------------------------------------------------------------
__global__ void final_out_kernel(const float* __restrict__ x,
                                 const float* __restrict__ r,
                                 float* __restrict__ out)
{
    __shared__ float tile[32][33];    // [t'][d']
    const int d0 = blockIdx.x * 32, t0 = blockIdx.y * 32, n = blockIdx.z;
    const int tx = threadIdx.x, ty = threadIdx.y;
#pragma unroll
    for (int s = 0; s < 4; ++s) {
        int tt = ty + s * 8;
        tile[tt][tx] = r[(size_t)(n * 256 + t0 + tt) * DDIM + d0 + tx];
    }
    __syncthreads();
    const float* xp = x + (size_t)n * (DDIM * 256);
    float* op = out + (size_t)n * (DDIM * 256);
#pragma unroll
    for (int s = 0; s < 4; ++s) {
        int dd = ty + s * 8;
        size_t off = (size_t)(d0 + dd) * 256 + t0 + tx;
        op[off] = xp[off] - tile[tx][dd];
    }
}

// --------------------------------------------------------------------------
// scalars: mean commit loss + mean perplexity
// --------------------------------------------------------------------------
__global__ __launch_bounds__(256) void scalars_kernel(
    const unsigned int* __restrict__ hist, const float* __restrict__ loss_bins,
    float* __restrict__ out2)
{
    __shared__ float red[4];
    __shared__ float perp_acc;
    const int tid = threadIdx.x, wave = tid >> 6, lane = tid & 63;
    if (tid == 0) perp_acc = 0.f;
    __syncthreads();
    for (int q = 0; q < QSTAGE; ++q) {
        float s = 0.f;
        for (int c = tid; c < CCODES; c += 256) {
            float p = (float)hist[q * CCODES + c] * (1.0f / (float)NTROWS);
            s += p * logf(p + 1e-10f);
        }
        s = wave_sum(s);
        if (lane == 0) red[wave] = s;
        __syncthreads();
        if (tid == 0) {
            float tot = red[0] + red[1] + red[2] + red[3];
            perp_acc += expf(-tot);
        }
        __syncthreads();
    }
    // parallel loss-bin sum
    float ls = 0.f;
    for (int i = tid; i < QSTAGE * 256; i += 256) ls += loss_bins[i];
    ls = wave_sum(ls);
    if (lane == 0) red[wave] = ls;
    __syncthreads();
    if (tid == 0) {
        float lsum = red[0] + red[1] + red[2] + red[3];
        out2[0] = (lsum / (float)QSTAGE) / ((float)NTROWS * (float)DDIM);
        out2[1] = perp_acc / (float)QSTAGE;
    }
}

// --------------------------------------------------------------------------
extern "C" void kernel_launch(void* const* d_in, const int* in_sizes, int n_in,
                              void* d_out, int out_size, void* d_ws, size_t ws_size,
                              hipStream_t stream)
{
    const float* x  = (const float*)d_in[0];
    const float* cb = (const float*)d_in[1];
    float* out = (float*)d_out;
    char* ws = (char*)d_ws;

    float*          r      = (float*)(ws + OFF_R);
    unsigned short* rbf    = (unsigned short*)(ws + OFF_RBF);
    unsigned short* cbbf   = (unsigned short*)(ws + OFF_CBBF);
    float*          cand   = (float*)(ws + OFF_CAND);
    float*          cbsq   = (float*)(ws + OFF_CBSQ);
    unsigned int*   hist   = (unsigned int*)(ws + OFF_HIST);
    float*          lbins  = (float*)(ws + OFF_LOSS);

    prep_cb_kernel<<<1536, 256, 0, stream>>>(cb, cbbf, cbsq, hist, lbins);
    prep_x_kernel<<<dim3(16, 8, 64), dim3(32, 8), 0, stream>>>(x, r, rbf);

    for (int q = 0; q < QSTAGE; ++q) {
        const size_t cboff = (size_t)q * CCODES * DDIM;
        gemm_dist_kernel<<<dim3(8, 128), 256, 0, stream>>>(
            rbf, cbbf + cboff, cbsq + q * CCODES, cand);
        refine_kernel<<<4096, 256, 0, stream>>>(
            r, rbf, cb + cboff, cbsq + q * CCODES, cand,
            out + OUT_IDX_OFF, hist + q * CCODES, lbins,
            q, (q < QSTAGE - 1) ? 1 : 0);
    }

    final_out_kernel<<<dim3(16, 8, 64), dim3(32, 8), 0, stream>>>(x, r, out);
    scalars_kernel<<<1, 256, 0, stream>>>(hist, lbins, out + OUT_SCAL_OFF);
}

// Round 4
// 503.617 us; speedup vs baseline: 1.2954x; 1.2954x over previous
//
#include <hip/hip_runtime.h>
#include <hip/hip_fp16.h>
#include <hip/hip_bf16.h>
#include <stdint.h>

// ---------------------------------------------------------------------------
// ResidualVQ: x (64,512,256) f32, codebooks (6,1024,512) f32
// outputs: quantized_out (64,512,256), indices (64,256,6) as f32,
//          mean_loss, mean_perplexity   -> d_out flat f32, 8486914 elems
//
// R3 -> R4 (all in gemm_dist_kernel):
//  a) top-2 epilogue now operates on packed u32 keys ((fkey(dist)&~1023)|col)
//     -> merge step = 2 shfl + 4 min/max instead of 4 shfl + ~14 cmp/cndmask.
//     cand table: NT x 16 groups x 2 u32 (2 MB).
//  b) grid (128,8), tm=blockIdx.x: same-tm blocks land on same XCD (id%8
//     = tm%8) -> A-tile fetched once per XCD L2 (FETCH 66.8 -> ~26 MB).
//  c) LDS xor chunk swizzle: lane stages global chunk (lane&3)^((lane>>3)&3);
//     reads use chunk quad^((l15>>1)&3) -> b128 reads spread over all 8
//     bank-quads (8-way -> 2-way, free per m136).
// ---------------------------------------------------------------------------

#define NTROWS 16384
#define DDIM   512
#define CCODES 1024
#define QSTAGE 6

// ws layout (bytes)
#define OFF_R      ((size_t)0)           // fp32 residual  NT*D*4   = 33554432
#define OFF_RBF    ((size_t)33554432)    // bf16 residual  NT*D*2   = 16777216
#define OFF_CBBF   ((size_t)50331648)    // bf16 codebooks 6*1024*512*2 = 6291456
#define OFF_CAND   ((size_t)56623104)    // u32 cand       NT*32*4   = 2097152
#define OFF_CBSQ   ((size_t)58720256)    // f32 |c|^2, 6*1024*4
#define OFF_HIST   ((size_t)58744832)    // u32 hist, 6*1024*4
#define OFF_LOSS   ((size_t)58769408)    // f32 loss bins, 6*256*4
#define WS_END     ((size_t)58775552)

#define OUT_IDX_OFF  ((size_t)8388608)
#define OUT_SCAL_OFF ((size_t)8486912)

typedef __attribute__((ext_vector_type(8))) short short8;
typedef __attribute__((ext_vector_type(8))) unsigned short ushort8v;
typedef __attribute__((ext_vector_type(4))) float f32x4;

__device__ __forceinline__ unsigned short f2bf(float f) {
    uint32_t u = __float_as_uint(f);
    uint32_t r = (u + 0x7fffu + ((u >> 16) & 1u)) >> 16;   // RNE
    return (unsigned short)r;
}
__device__ __forceinline__ uint32_t fkey(float f) {        // order-preserving f32->u32
    uint32_t u = __float_as_uint(f);
    return u ^ ((uint32_t)((int32_t)u >> 31) | 0x80000000u);
}
__device__ __forceinline__ float funkey(uint32_t k) {
    uint32_t u = (k & 0x80000000u) ? (k ^ 0x80000000u) : ~k;
    return __uint_as_float(u);
}
__device__ __forceinline__ uint32_t umin32(uint32_t a, uint32_t b) { return a < b ? a : b; }
__device__ __forceinline__ uint32_t umax32(uint32_t a, uint32_t b) { return a > b ? a : b; }
__device__ __forceinline__ float wave_sum(float v) {
    for (int m = 32; m; m >>= 1) v += __shfl_xor(v, m, 64);
    return v;
}
__device__ __forceinline__ uint32_t wave_min_u32(uint32_t v) {
    for (int m = 32; m; m >>= 1) v = umin32(v, (uint32_t)__shfl_xor((int)v, m, 64));
    return v;
}
__device__ __forceinline__ void async_load16(const void* g, void* l) {
    __builtin_amdgcn_global_load_lds(
        (__attribute__((address_space(1))) void*)(void*)g,
        (__attribute__((address_space(3))) void*)l, 16, 0, 0);
}

// --------------------------------------------------------------------------
// prep_cb: bf16 codebooks + |c|^2 ; also zero hist/loss bins (block 0)
// grid 1536 x 256 (wave per code row)
// --------------------------------------------------------------------------
__global__ __launch_bounds__(256) void prep_cb_kernel(
    const float* __restrict__ cb, unsigned short* __restrict__ cbbf,
    float* __restrict__ cbsq, unsigned int* __restrict__ hist,
    float* __restrict__ loss_bins)
{
    const int wave = threadIdx.x >> 6, lane = threadIdx.x & 63;
    const int row = blockIdx.x * 4 + wave;            // 0..6143
    const float* p = cb + (size_t)row * DDIM;
    unsigned short* pb = cbbf + (size_t)row * DDIM;
    float s = 0.f;
#pragma unroll
    for (int t = 0; t < 8; ++t) {
        float v = p[lane + 64 * t];
        pb[lane + 64 * t] = f2bf(v);
        s += v * v;
    }
    s = wave_sum(s);
    if (lane == 0) cbsq[row] = s;
    if (blockIdx.x == 0) {
        for (int i = threadIdx.x; i < QSTAGE * CCODES; i += 256) hist[i] = 0u;
        for (int i = threadIdx.x; i < QSTAGE * 256; i += 256) loss_bins[i] = 0.f;
    }
}

// --------------------------------------------------------------------------
// prep_x: transpose x (N,D,T) -> r (NT,D) fp32+bf16
// grid (16,8,64) block (32,8)
// --------------------------------------------------------------------------
__global__ void prep_x_kernel(const float* __restrict__ x, float* __restrict__ r,
                              unsigned short* __restrict__ rbf)
{
    __shared__ float tile[32][33];
    const int d0 = blockIdx.x * 32, t0 = blockIdx.y * 32, n = blockIdx.z;
    const int tx = threadIdx.x, ty = threadIdx.y;
    const float* xp = x + (size_t)n * (DDIM * 256);
#pragma unroll
    for (int s = 0; s < 4; ++s) {
        int dd = ty + s * 8;
        tile[dd][tx] = xp[(size_t)(d0 + dd) * 256 + t0 + tx];
    }
    __syncthreads();
#pragma unroll
    for (int s = 0; s < 4; ++s) {
        int tt = ty + s * 8;
        float v = tile[tx][tt];
        size_t off = (size_t)(n * 256 + t0 + tt) * DDIM + d0 + tx;
        r[off] = v;
        rbf[off] = f2bf(v);
    }
}

// --------------------------------------------------------------------------
// GEMM: dist'[row][col] = cbsq[col] - 2 * dot(r_row, c_col), bf16 MFMA.
// Epilogue: packed-u32 top-2 per (row, 64-col wave-group) -> cand table.
// grid (128, 8) x 256 : tm = blockIdx.x (XCD swizzle), tn = blockIdx.y
// --------------------------------------------------------------------------
__global__ __launch_bounds__(256) void gemm_dist_kernel(
    const unsigned short* __restrict__ Abf,   // NT x 512 bf16
    const unsigned short* __restrict__ Bbf,   // 1024 x 512 bf16 (stage slice)
    const float* __restrict__ cbsq,           // 1024 (stage slice)
    uint32_t* __restrict__ cand)              // NT x 16 x {k1,k2}
{
    __shared__ __align__(16) unsigned short lA[128 * 32];
    __shared__ __align__(16) unsigned short lB[128 * 32];
    const int tid = threadIdx.x;
    const int wave = tid >> 6, lane = tid & 63;
    const int quad = lane >> 4, l15 = lane & 15;
    const int tm = blockIdx.x, tn = blockIdx.y;
    const int wm = wave & 1, wn = wave >> 1;

    f32x4 acc[4][4];
#pragma unroll
    for (int i = 0; i < 4; ++i)
#pragma unroll
        for (int j = 0; j < 4; ++j) acc[i][j] = (f32x4){0.f, 0.f, 0.f, 0.f};

    // staging: wave w loads rows [w*16 + lane>>2] and +64.
    // xor chunk swizzle: lane stages global 16B-chunk (lane&3)^xq where
    // xq = (srow>>1)&3 = (lane>>3)&3. LDS dest stays linear (lane*16).
    const int srow = wave * 16 + (lane >> 2);
    const int gchunk = (lane & 3) ^ ((lane >> 3) & 3);
    const unsigned short* gA0 = Abf + (size_t)(tm * 128 + srow) * DDIM + gchunk * 8;
    const unsigned short* gA1 = gA0 + 64 * DDIM;
    const unsigned short* gB0 = Bbf + (size_t)(tn * 128 + srow) * DDIM + gchunk * 8;
    const unsigned short* gB1 = gB0 + 64 * DDIM;
    unsigned short* sA0 = &lA[srow * 32 + (lane & 3) * 8];
    unsigned short* sA1 = &lA[(64 + srow) * 32 + (lane & 3) * 8];
    unsigned short* sB0 = &lB[srow * 32 + (lane & 3) * 8];
    unsigned short* sB1 = &lB[(64 + srow) * 32 + (lane & 3) * 8];

    for (int kt = 0; kt < DDIM / 32; ++kt) {
        async_load16(gA0, sA0); async_load16(gA1, sA1);
        async_load16(gB0, sB0); async_load16(gB1, sB1);
        gA0 += 32; gA1 += 32; gB0 += 32; gB1 += 32;
        __syncthreads();   // drains vmcnt before LDS reads
        short8 af[4], bfr[4];
        const int cqa = (quad ^ ((l15 >> 1) & 3)) * 8;   // swizzled chunk addr
#pragma unroll
        for (int i = 0; i < 4; ++i)
            af[i] = *(const short8*)&lA[(wm * 64 + i * 16 + l15) * 32 + cqa];
#pragma unroll
        for (int j = 0; j < 4; ++j)
            bfr[j] = *(const short8*)&lB[(wn * 64 + j * 16 + l15) * 32 + cqa];
#pragma unroll
        for (int i = 0; i < 4; ++i)
#pragma unroll
            for (int j = 0; j < 4; ++j)
                acc[i][j] = __builtin_amdgcn_mfma_f32_16x16x32_bf16(
                    af[i], bfr[j], acc[i][j], 0, 0, 0);
        __syncthreads();   // before next tile overwrites LDS
    }

    // epilogue: C/D layout col=lane&15, row=quad*4+reg (m89-verified).
    // Packed top-2 per row over this wave's 64 cols.
    const int rowbase = tm * 128 + wm * 64 + quad * 4;
    const int colbase = tn * 128 + wn * 64 + l15;
    const int g = tn * 2 + wn;                 // 64-col group index, 0..15
    float cbs[4];
#pragma unroll
    for (int j = 0; j < 4; ++j) cbs[j] = cbsq[colbase + j * 16];
#pragma unroll
    for (int i = 0; i < 4; ++i) {
#pragma unroll
        for (int reg = 0; reg < 4; ++reg) {
            uint32_t k[4];
#pragma unroll
            for (int j = 0; j < 4; ++j) {
                float dv = cbs[j] - 2.0f * acc[i][j][reg];
                k[j] = (fkey(dv) & ~1023u) | (uint32_t)(colbase + j * 16);
            }
            // top-2 of 4 (tournament)
            uint32_t m01 = umin32(k[0], k[1]), M01 = umax32(k[0], k[1]);
            uint32_t m23 = umin32(k[2], k[3]), M23 = umax32(k[2], k[3]);
            uint32_t k1 = umin32(m01, m23);
            uint32_t k2 = umin32(umax32(m01, m23), umin32(M01, M23));
            // merge across the 16 lanes of this quad (xor masks stay in-quad)
#pragma unroll
            for (int m = 1; m < 16; m <<= 1) {
                uint32_t o1 = (uint32_t)__shfl_xor((int)k1, m, 64);
                uint32_t o2 = (uint32_t)__shfl_xor((int)k2, m, 64);
                uint32_t n1 = umin32(k1, o1);
                uint32_t n2 = umin32(umax32(k1, o1), umin32(k2, o2));
                k1 = n1; k2 = n2;
            }
            if (l15 == 0) {
                const int row = rowbase + i * 16 + reg;
                *(uint2*)&cand[((size_t)row * 16 + g) * 2] = make_uint2(k1, k2);
            }
        }
    }
}

// --------------------------------------------------------------------------
// refine+update: read 32 packed candidates/row, exact fp32 recompute for all
// entries within MARGIN of approx min; r -= cb[best]; write fp32+bf16;
// loss += best (256-bin atomics); hist; index out.
// grid 4096 x 256 (wave per row, lane owns 8 contiguous d)
// --------------------------------------------------------------------------
#define MARGIN 8.0f
__global__ __launch_bounds__(256) void refine_kernel(
    float* __restrict__ r, unsigned short* __restrict__ rbf,
    const float* __restrict__ cbq, const float* __restrict__ cbsqq,
    const uint32_t* __restrict__ cand,
    float* __restrict__ out_idx, unsigned int* __restrict__ histq,
    float* __restrict__ loss_bins, int q, int write_bf)
{
    const int wave = threadIdx.x >> 6, lane = threadIdx.x & 63;
    const int nt = blockIdx.x * 4 + wave;

    const float4* r4 = (const float4*)(r + (size_t)nt * DDIM);
    float4 ra = r4[lane * 2], rb = r4[lane * 2 + 1];
    float s = ra.x * ra.x + ra.y * ra.y + ra.z * ra.z + ra.w * ra.w
            + rb.x * rb.x + rb.y * rb.y + rb.z * rb.z + rb.w * rb.w;
    const float sumx = wave_sum(s);

    uint32_t key = 0xFFFFFFFFu;
    if (lane < 32) key = cand[(size_t)nt * 32 + lane];
    const uint32_t kmin = wave_min_u32(key);
    const float thr = funkey(kmin & ~1023u) + MARGIN;

    unsigned long long mask = __ballot(lane < 32 && funkey(key & ~1023u) <= thr);

    float best = 1e30f;
    int bestc = CCODES;
    while (mask) {
        const int src = __ffsll(mask) - 1;
        mask &= mask - 1;
        const int cc = __shfl((int)(key & 1023u), src, 64);
        const float4* crow = (const float4*)(cbq + (size_t)cc * DDIM);
        float4 ca = crow[lane * 2], cb2 = crow[lane * 2 + 1];
        float dot = ra.x * ca.x + ra.y * ca.y + ra.z * ca.z + ra.w * ca.w
                  + rb.x * cb2.x + rb.y * cb2.y + rb.z * cb2.z + rb.w * cb2.w;
        dot = wave_sum(dot);
        const float de = (sumx - 2.0f * dot) + cbsqq[cc];
        if (de < best || (de == best && cc < bestc)) { best = de; bestc = cc; }
    }

    // merged residual update: bestc/best are wave-uniform
    const float4* cbest = (const float4*)(cbq + (size_t)bestc * DDIM);
    float4 ba = cbest[lane * 2], bb = cbest[lane * 2 + 1];
    float4 na = make_float4(ra.x - ba.x, ra.y - ba.y, ra.z - ba.z, ra.w - ba.w);
    float4 nb = make_float4(rb.x - bb.x, rb.y - bb.y, rb.z - bb.z, rb.w - bb.w);
    float4* rw = (float4*)(r + (size_t)nt * DDIM);
    rw[lane * 2] = na; rw[lane * 2 + 1] = nb;
    if (write_bf) {
        ushort8v pk;
        pk[0] = f2bf(na.x); pk[1] = f2bf(na.y); pk[2] = f2bf(na.z); pk[3] = f2bf(na.w);
        pk[4] = f2bf(nb.x); pk[5] = f2bf(nb.y); pk[6] = f2bf(nb.z); pk[7] = f2bf(nb.w);
        *(ushort8v*)(rbf + (size_t)nt * DDIM + lane * 8) = pk;
    }

    if (lane == 0) {
        out_idx[(size_t)nt * QSTAGE + q] = (float)bestc;
        atomicAdd(&histq[bestc], 1u);
        atomicAdd(&loss_bins[q * 256 + (blockIdx.x & 255)], best);
    }
}

// --------------------------------------------------------------------------
// final: out = x - r_final, transposed back to (N,D,T)
// grid (16,8,64) block (32,8)
// --------------------------------------------------------------------------
__global__ void final_out_kernel(const float* __restrict__ x,
                                 const float* __restrict__ r,
                                 float* __restrict__ out)
{
    __shared__ float tile[32][33];    // [t'][d']
    const int d0 = blockIdx.x * 32, t0 = blockIdx.y * 32, n = blockIdx.z;
    const int tx = threadIdx.x, ty = threadIdx.y;
#pragma unroll
    for (int s = 0; s < 4; ++s) {
        int tt = ty + s * 8;
        tile[tt][tx] = r[(size_t)(n * 256 + t0 + tt) * DDIM + d0 + tx];
    }
    __syncthreads();
    const float* xp = x + (size_t)n * (DDIM * 256);
    float* op = out + (size_t)n * (DDIM * 256);
#pragma unroll
    for (int s = 0; s < 4; ++s) {
        int dd = ty + s * 8;
        size_t off = (size_t)(d0 + dd) * 256 + t0 + tx;
        op[off] = xp[off] - tile[tx][dd];
    }
}

// --------------------------------------------------------------------------
// scalars: mean commit loss + mean perplexity
// --------------------------------------------------------------------------
__global__ __launch_bounds__(256) void scalars_kernel(
    const unsigned int* __restrict__ hist, const float* __restrict__ loss_bins,
    float* __restrict__ out2)
{
    __shared__ float red[4];
    __shared__ float perp_acc;
    const int tid = threadIdx.x, wave = tid >> 6, lane = tid & 63;
    if (tid == 0) perp_acc = 0.f;
    __syncthreads();
    for (int q = 0; q < QSTAGE; ++q) {
        float s = 0.f;
        for (int c = tid; c < CCODES; c += 256) {
            float p = (float)hist[q * CCODES + c] * (1.0f / (float)NTROWS);
            s += p * logf(p + 1e-10f);
        }
        s = wave_sum(s);
        if (lane == 0) red[wave] = s;
        __syncthreads();
        if (tid == 0) {
            float tot = red[0] + red[1] + red[2] + red[3];
            perp_acc += expf(-tot);
        }
        __syncthreads();
    }
    // parallel loss-bin sum
    float ls = 0.f;
    for (int i = tid; i < QSTAGE * 256; i += 256) ls += loss_bins[i];
    ls = wave_sum(ls);
    if (lane == 0) red[wave] = ls;
    __syncthreads();
    if (tid == 0) {
        float lsum = red[0] + red[1] + red[2] + red[3];
        out2[0] = (lsum / (float)QSTAGE) / ((float)NTROWS * (float)DDIM);
        out2[1] = perp_acc / (float)QSTAGE;
    }
}

// --------------------------------------------------------------------------
extern "C" void kernel_launch(void* const* d_in, const int* in_sizes, int n_in,
                              void* d_out, int out_size, void* d_ws, size_t ws_size,
                              hipStream_t stream)
{
    const float* x  = (const float*)d_in[0];
    const float* cb = (const float*)d_in[1];
    float* out = (float*)d_out;
    char* ws = (char*)d_ws;

    float*          r      = (float*)(ws + OFF_R);
    unsigned short* rbf    = (unsigned short*)(ws + OFF_RBF);
    unsigned short* cbbf   = (unsigned short*)(ws + OFF_CBBF);
    uint32_t*       cand   = (uint32_t*)(ws + OFF_CAND);
    float*          cbsq   = (float*)(ws + OFF_CBSQ);
    unsigned int*   hist   = (unsigned int*)(ws + OFF_HIST);
    float*          lbins  = (float*)(ws + OFF_LOSS);

    prep_cb_kernel<<<1536, 256, 0, stream>>>(cb, cbbf, cbsq, hist, lbins);
    prep_x_kernel<<<dim3(16, 8, 64), dim3(32, 8), 0, stream>>>(x, r, rbf);

    for (int q = 0; q < QSTAGE; ++q) {
        const size_t cboff = (size_t)q * CCODES * DDIM;
        gemm_dist_kernel<<<dim3(128, 8), 256, 0, stream>>>(
            rbf, cbbf + cboff, cbsq + q * CCODES, cand);
        refine_kernel<<<4096, 256, 0, stream>>>(
            r, rbf, cb + cboff, cbsq + q * CCODES, cand,
            out + OUT_IDX_OFF, hist + q * CCODES, lbins,
            q, (q < QSTAGE - 1) ? 1 : 0);
    }

    final_out_kernel<<<dim3(16, 8, 64), dim3(32, 8), 0, stream>>>(x, r, out);
    scalars_kernel<<<1, 256, 0, stream>>>(hist, lbins, out + OUT_SCAL_OFF);
}

// Round 5
// 476.046 us; speedup vs baseline: 1.3704x; 1.0579x over previous
//
#include <hip/hip_runtime.h>
#include <hip/hip_fp16.h>
#include <hip/hip_bf16.h>
#include <stdint.h>

// ---------------------------------------------------------------------------
// ResidualVQ: x (64,512,256) f32, codebooks (6,1024,512) f32
// outputs: quantized_out (64,512,256), indices (64,256,6) as f32,
//          mean_loss, mean_perplexity   -> d_out flat f32, 8486914 elems
//
// R4 -> R5:
//  a) gemm tile 128x128 -> 128x256 (grid (128,4)): 32 MFMA/wave/K-iter vs 16,
//     staging 6 issues vs 4, LDS bytes/MFMA 512->384. acc = 128 VGPRs,
//     __launch_bounds__(256,2). Short-K (16 iters) amortization was the
//     bottleneck (gemm ran ~450 TF vs m97's ~900 TF plateau).
//  b) prep_cb+prep_x fused into one prep_kernel; final_out+scalars fused.
//     14 dispatches total (was 16).
// ---------------------------------------------------------------------------

#define NTROWS 16384
#define DDIM   512
#define CCODES 1024
#define QSTAGE 6

// ws layout (bytes)
#define OFF_R      ((size_t)0)           // fp32 residual  NT*D*4   = 33554432
#define OFF_RBF    ((size_t)33554432)    // bf16 residual  NT*D*2   = 16777216
#define OFF_CBBF   ((size_t)50331648)    // bf16 codebooks 6*1024*512*2 = 6291456
#define OFF_CAND   ((size_t)56623104)    // u32 cand       NT*32*4   = 2097152
#define OFF_CBSQ   ((size_t)58720256)    // f32 |c|^2, 6*1024*4
#define OFF_HIST   ((size_t)58744832)    // u32 hist, 6*1024*4
#define OFF_LOSS   ((size_t)58769408)    // f32 loss bins, 6*256*4
#define WS_END     ((size_t)58775552)

#define OUT_IDX_OFF  ((size_t)8388608)
#define OUT_SCAL_OFF ((size_t)8486912)

typedef __attribute__((ext_vector_type(8))) short short8;
typedef __attribute__((ext_vector_type(8))) unsigned short ushort8v;
typedef __attribute__((ext_vector_type(4))) float f32x4;

__device__ __forceinline__ unsigned short f2bf(float f) {
    uint32_t u = __float_as_uint(f);
    uint32_t r = (u + 0x7fffu + ((u >> 16) & 1u)) >> 16;   // RNE
    return (unsigned short)r;
}
__device__ __forceinline__ uint32_t fkey(float f) {        // order-preserving f32->u32
    uint32_t u = __float_as_uint(f);
    return u ^ ((uint32_t)((int32_t)u >> 31) | 0x80000000u);
}
__device__ __forceinline__ float funkey(uint32_t k) {
    uint32_t u = (k & 0x80000000u) ? (k ^ 0x80000000u) : ~k;
    return __uint_as_float(u);
}
__device__ __forceinline__ uint32_t umin32(uint32_t a, uint32_t b) { return a < b ? a : b; }
__device__ __forceinline__ uint32_t umax32(uint32_t a, uint32_t b) { return a > b ? a : b; }
__device__ __forceinline__ float wave_sum(float v) {
    for (int m = 32; m; m >>= 1) v += __shfl_xor(v, m, 64);
    return v;
}
__device__ __forceinline__ uint32_t wave_min_u32(uint32_t v) {
    for (int m = 32; m; m >>= 1) v = umin32(v, (uint32_t)__shfl_xor((int)v, m, 64));
    return v;
}
__device__ __forceinline__ void async_load16(const void* g, void* l) {
    __builtin_amdgcn_global_load_lds(
        (__attribute__((address_space(1))) void*)(void*)g,
        (__attribute__((address_space(3))) void*)l, 16, 0, 0);
}

// --------------------------------------------------------------------------
// prep: blocks [0,1536): bf16 codebooks + |c|^2 (+ zero hist/loss in blk 0)
//       blocks [1536,9728): transpose x (N,D,T) -> r (NT,D) fp32+bf16
// grid 9728 x 256
// --------------------------------------------------------------------------
__global__ __launch_bounds__(256) void prep_kernel(
    const float* __restrict__ x, const float* __restrict__ cb,
    float* __restrict__ r, unsigned short* __restrict__ rbf,
    unsigned short* __restrict__ cbbf, float* __restrict__ cbsq,
    unsigned int* __restrict__ hist, float* __restrict__ loss_bins)
{
    __shared__ float tile[32][33];
    if (blockIdx.x < 1536) {
        const int wave = threadIdx.x >> 6, lane = threadIdx.x & 63;
        const int row = blockIdx.x * 4 + wave;            // 0..6143
        const float* p = cb + (size_t)row * DDIM;
        unsigned short* pb = cbbf + (size_t)row * DDIM;
        float s = 0.f;
#pragma unroll
        for (int t = 0; t < 8; ++t) {
            float v = p[lane + 64 * t];
            pb[lane + 64 * t] = f2bf(v);
            s += v * v;
        }
        s = wave_sum(s);
        if (lane == 0) cbsq[row] = s;
        if (blockIdx.x == 0) {
            for (int i = threadIdx.x; i < QSTAGE * CCODES; i += 256) hist[i] = 0u;
            for (int i = threadIdx.x; i < QSTAGE * 256; i += 256) loss_bins[i] = 0.f;
        }
    } else {
        const int bidx = blockIdx.x - 1536;               // 0..8191
        const int d0 = (bidx & 15) * 32;
        const int t0 = ((bidx >> 4) & 7) * 32;
        const int n  = bidx >> 7;
        const int tx = threadIdx.x & 31, ty = threadIdx.x >> 5;
        const float* xp = x + (size_t)n * (DDIM * 256);
#pragma unroll
        for (int s = 0; s < 4; ++s) {
            int dd = ty + s * 8;
            tile[dd][tx] = xp[(size_t)(d0 + dd) * 256 + t0 + tx];
        }
        __syncthreads();
#pragma unroll
        for (int s = 0; s < 4; ++s) {
            int tt = ty + s * 8;
            float v = tile[tx][tt];
            size_t off = (size_t)(n * 256 + t0 + tt) * DDIM + d0 + tx;
            r[off] = v;
            rbf[off] = f2bf(v);
        }
    }
}

// --------------------------------------------------------------------------
// GEMM: dist'[row][col] = cbsq[col] - 2 * dot(r_row, c_col), bf16 MFMA.
// 128x256 block tile; epilogue: packed-u32 top-2 per (row, 64-col group).
// grid (128, 4) x 256 : tm = blockIdx.x (XCD swizzle), tn2 = blockIdx.y
// --------------------------------------------------------------------------
__global__ __launch_bounds__(256, 2) void gemm_dist_kernel(
    const unsigned short* __restrict__ Abf,   // NT x 512 bf16
    const unsigned short* __restrict__ Bbf,   // 1024 x 512 bf16 (stage slice)
    const float* __restrict__ cbsq,           // 1024 (stage slice)
    uint32_t* __restrict__ cand)              // NT x 16 x {k1,k2}
{
    __shared__ __align__(16) unsigned short lA[128 * 32];
    __shared__ __align__(16) unsigned short lB[256 * 32];
    const int tid = threadIdx.x;
    const int wave = tid >> 6, lane = tid & 63;
    const int quad = lane >> 4, l15 = lane & 15;
    const int tm = blockIdx.x, tn2 = blockIdx.y;
    const int wm = wave & 1, wn = wave >> 1;

    f32x4 acc[4][8];
#pragma unroll
    for (int i = 0; i < 4; ++i)
#pragma unroll
        for (int j = 0; j < 8; ++j) acc[i][j] = (f32x4){0.f, 0.f, 0.f, 0.f};

    // staging: wave w owns rows [w*16 + lane>>2] (+64/+128/+192 for B).
    // xor chunk swizzle: lane stages global 16B-chunk (lane&3)^((lane>>3)&3);
    // LDS dest stays linear (lane&3).
    const int srow = wave * 16 + (lane >> 2);
    const int gchunk = (lane & 3) ^ ((lane >> 3) & 3);
    const unsigned short* gA0 = Abf + (size_t)(tm * 128 + srow) * DDIM + gchunk * 8;
    const unsigned short* gA1 = gA0 + 64 * DDIM;
    const unsigned short* gB0 = Bbf + (size_t)(tn2 * 256 + srow) * DDIM + gchunk * 8;
    const unsigned short* gB1 = gB0 + 64 * DDIM;
    const unsigned short* gB2 = gB0 + 128 * DDIM;
    const unsigned short* gB3 = gB0 + 192 * DDIM;
    unsigned short* sA0 = &lA[srow * 32 + (lane & 3) * 8];
    unsigned short* sA1 = &lA[(64 + srow) * 32 + (lane & 3) * 8];
    unsigned short* sB0 = &lB[srow * 32 + (lane & 3) * 8];
    unsigned short* sB1 = &lB[(64 + srow) * 32 + (lane & 3) * 8];
    unsigned short* sB2 = &lB[(128 + srow) * 32 + (lane & 3) * 8];
    unsigned short* sB3 = &lB[(192 + srow) * 32 + (lane & 3) * 8];

    for (int kt = 0; kt < DDIM / 32; ++kt) {
        async_load16(gA0, sA0); async_load16(gA1, sA1);
        async_load16(gB0, sB0); async_load16(gB1, sB1);
        async_load16(gB2, sB2); async_load16(gB3, sB3);
        gA0 += 32; gA1 += 32; gB0 += 32; gB1 += 32; gB2 += 32; gB3 += 32;
        __syncthreads();   // drains vmcnt before LDS reads
        const int cqa = (quad ^ ((l15 >> 1) & 3)) * 8;   // swizzled chunk addr
        short8 af[4], bfr[8];
#pragma unroll
        for (int i = 0; i < 4; ++i)
            af[i] = *(const short8*)&lA[(wm * 64 + i * 16 + l15) * 32 + cqa];
#pragma unroll
        for (int j = 0; j < 8; ++j)
            bfr[j] = *(const short8*)&lB[(wn * 128 + j * 16 + l15) * 32 + cqa];
#pragma unroll
        for (int i = 0; i < 4; ++i)
#pragma unroll
            for (int j = 0; j < 8; ++j)
                acc[i][j] = __builtin_amdgcn_mfma_f32_16x16x32_bf16(
                    af[i], bfr[j], acc[i][j], 0, 0, 0);
        __syncthreads();   // before next tile overwrites LDS
    }

    // epilogue: C/D layout col=lane&15, row=quad*4+reg (m89-verified).
    // Packed top-2 per row per 64-col group (two groups per wave).
    const int rowbase = tm * 128 + wm * 64 + quad * 4;
    const int colbase = tn2 * 256 + wn * 128 + l15;
    const int gbase = tn2 * 4 + wn * 2;        // 64-col group index base
    float cbs[8];
#pragma unroll
    for (int j = 0; j < 8; ++j) cbs[j] = cbsq[colbase + j * 16];
#pragma unroll
    for (int i = 0; i < 4; ++i) {
#pragma unroll
        for (int reg = 0; reg < 4; ++reg) {
            const int row = rowbase + i * 16 + reg;
#pragma unroll
            for (int jh = 0; jh < 2; ++jh) {
                uint32_t k[4];
#pragma unroll
                for (int jj = 0; jj < 4; ++jj) {
                    const int j = jh * 4 + jj;
                    float dv = cbs[j] - 2.0f * acc[i][j][reg];
                    k[jj] = (fkey(dv) & ~1023u) | (uint32_t)(colbase + j * 16);
                }
                // top-2 of 4 (tournament)
                uint32_t m01 = umin32(k[0], k[1]), M01 = umax32(k[0], k[1]);
                uint32_t m23 = umin32(k[2], k[3]), M23 = umax32(k[2], k[3]);
                uint32_t k1 = umin32(m01, m23);
                uint32_t k2 = umin32(umax32(m01, m23), umin32(M01, M23));
                // merge across the 16 lanes of this quad (xor stays in-quad)
#pragma unroll
                for (int m = 1; m < 16; m <<= 1) {
                    uint32_t o1 = (uint32_t)__shfl_xor((int)k1, m, 64);
                    uint32_t o2 = (uint32_t)__shfl_xor((int)k2, m, 64);
                    uint32_t n1 = umin32(k1, o1);
                    uint32_t n2 = umin32(umax32(k1, o1), umin32(k2, o2));
                    k1 = n1; k2 = n2;
                }
                if (l15 == 0)
                    *(uint2*)&cand[((size_t)row * 16 + gbase + jh) * 2] =
                        make_uint2(k1, k2);
            }
        }
    }
}

// --------------------------------------------------------------------------
// refine+update: read 32 packed candidates/row, exact fp32 recompute for all
// entries within MARGIN of approx min; r -= cb[best]; write fp32+bf16;
// loss += best (256-bin atomics); hist; index out.
// grid 4096 x 256 (wave per row, lane owns 8 contiguous d)
// --------------------------------------------------------------------------
#define MARGIN 8.0f
__global__ __launch_bounds__(256) void refine_kernel(
    float* __restrict__ r, unsigned short* __restrict__ rbf,
    const float* __restrict__ cbq, const float* __restrict__ cbsqq,
    const uint32_t* __restrict__ cand,
    float* __restrict__ out_idx, unsigned int* __restrict__ histq,
    float* __restrict__ loss_bins, int q, int write_bf)
{
    const int wave = threadIdx.x >> 6, lane = threadIdx.x & 63;
    const int nt = blockIdx.x * 4 + wave;

    const float4* r4 = (const float4*)(r + (size_t)nt * DDIM);
    float4 ra = r4[lane * 2], rb = r4[lane * 2 + 1];
    float s = ra.x * ra.x + ra.y * ra.y + ra.z * ra.z + ra.w * ra.w
            + rb.x * rb.x + rb.y * rb.y + rb.z * rb.z + rb.w * rb.w;
    const float sumx = wave_sum(s);

    uint32_t key = 0xFFFFFFFFu;
    if (lane < 32) key = cand[(size_t)nt * 32 + lane];
    const uint32_t kmin = wave_min_u32(key);
    const float thr = funkey(kmin & ~1023u) + MARGIN;

    unsigned long long mask = __ballot(lane < 32 && funkey(key & ~1023u) <= thr);

    float best = 1e30f;
    int bestc = CCODES;
    while (mask) {
        const int src = __ffsll(mask) - 1;
        mask &= mask - 1;
        const int cc = __shfl((int)(key & 1023u), src, 64);
        const float4* crow = (const float4*)(cbq + (size_t)cc * DDIM);
        float4 ca = crow[lane * 2], cb2 = crow[lane * 2 + 1];
        float dot = ra.x * ca.x + ra.y * ca.y + ra.z * ca.z + ra.w * ca.w
                  + rb.x * cb2.x + rb.y * cb2.y + rb.z * cb2.z + rb.w * cb2.w;
        dot = wave_sum(dot);
        const float de = (sumx - 2.0f * dot) + cbsqq[cc];
        if (de < best || (de == best && cc < bestc)) { best = de; bestc = cc; }
    }

    // merged residual update: bestc/best are wave-uniform
    const float4* cbest = (const float4*)(cbq + (size_t)bestc * DDIM);
    float4 ba = cbest[lane * 2], bb = cbest[lane * 2 + 1];
    float4 na = make_float4(ra.x - ba.x, ra.y - ba.y, ra.z - ba.z, ra.w - ba.w);
    float4 nb = make_float4(rb.x - bb.x, rb.y - bb.y, rb.z - bb.z, rb.w - bb.w);
    float4* rw = (float4*)(r + (size_t)nt * DDIM);
    rw[lane * 2] = na; rw[lane * 2 + 1] = nb;
    if (write_bf) {
        ushort8v pk;
        pk[0] = f2bf(na.x); pk[1] = f2bf(na.y); pk[2] = f2bf(na.z); pk[3] = f2bf(na.w);
        pk[4] = f2bf(nb.x); pk[5] = f2bf(nb.y); pk[6] = f2bf(nb.z); pk[7] = f2bf(nb.w);
        *(ushort8v*)(rbf + (size_t)nt * DDIM + lane * 8) = pk;
    }

    if (lane == 0) {
        out_idx[(size_t)nt * QSTAGE + q] = (float)bestc;
        atomicAdd(&histq[bestc], 1u);
        atomicAdd(&loss_bins[q * 256 + (blockIdx.x & 255)], best);
    }
}

// --------------------------------------------------------------------------
// final: blocks [0,8192): out = x - r_final transposed back to (N,D,T);
//        block 8192: mean commit loss + mean perplexity
// grid 8193 x 256
// --------------------------------------------------------------------------
__global__ __launch_bounds__(256) void final_kernel(
    const float* __restrict__ x, const float* __restrict__ r,
    float* __restrict__ out,
    const unsigned int* __restrict__ hist, const float* __restrict__ loss_bins,
    float* __restrict__ out2)
{
    __shared__ float tile[32][33];    // [t'][d']
    __shared__ float red[4];
    __shared__ float perp_acc;
    const int tid = threadIdx.x, wave = tid >> 6, lane = tid & 63;

    if (blockIdx.x < 8192) {
        const int bidx = blockIdx.x;
        const int d0 = (bidx & 15) * 32;
        const int t0 = ((bidx >> 4) & 7) * 32;
        const int n  = bidx >> 7;
        const int tx = tid & 31, ty = tid >> 5;
#pragma unroll
        for (int s = 0; s < 4; ++s) {
            int tt = ty + s * 8;
            tile[tt][tx] = r[(size_t)(n * 256 + t0 + tt) * DDIM + d0 + tx];
        }
        __syncthreads();
        const float* xp = x + (size_t)n * (DDIM * 256);
        float* op = out + (size_t)n * (DDIM * 256);
#pragma unroll
        for (int s = 0; s < 4; ++s) {
            int dd = ty + s * 8;
            size_t off = (size_t)(d0 + dd) * 256 + t0 + tx;
            op[off] = xp[off] - tile[tx][dd];
        }
        return;
    }

    // scalars block
    if (tid == 0) perp_acc = 0.f;
    __syncthreads();
    for (int q = 0; q < QSTAGE; ++q) {
        float s = 0.f;
        for (int c = tid; c < CCODES; c += 256) {
            float p = (float)hist[q * CCODES + c] * (1.0f / (float)NTROWS);
            s += p * logf(p + 1e-10f);
        }
        s = wave_sum(s);
        if (lane == 0) red[wave] = s;
        __syncthreads();
        if (tid == 0) {
            float tot = red[0] + red[1] + red[2] + red[3];
            perp_acc += expf(-tot);
        }
        __syncthreads();
    }
    float ls = 0.f;
    for (int i = tid; i < QSTAGE * 256; i += 256) ls += loss_bins[i];
    ls = wave_sum(ls);
    if (lane == 0) red[wave] = ls;
    __syncthreads();
    if (tid == 0) {
        float lsum = red[0] + red[1] + red[2] + red[3];
        out2[0] = (lsum / (float)QSTAGE) / ((float)NTROWS * (float)DDIM);
        out2[1] = perp_acc / (float)QSTAGE;
    }
}

// --------------------------------------------------------------------------
extern "C" void kernel_launch(void* const* d_in, const int* in_sizes, int n_in,
                              void* d_out, int out_size, void* d_ws, size_t ws_size,
                              hipStream_t stream)
{
    const float* x  = (const float*)d_in[0];
    const float* cb = (const float*)d_in[1];
    float* out = (float*)d_out;
    char* ws = (char*)d_ws;

    float*          r      = (float*)(ws + OFF_R);
    unsigned short* rbf    = (unsigned short*)(ws + OFF_RBF);
    unsigned short* cbbf   = (unsigned short*)(ws + OFF_CBBF);
    uint32_t*       cand   = (uint32_t*)(ws + OFF_CAND);
    float*          cbsq   = (float*)(ws + OFF_CBSQ);
    unsigned int*   hist   = (unsigned int*)(ws + OFF_HIST);
    float*          lbins  = (float*)(ws + OFF_LOSS);

    prep_kernel<<<9728, 256, 0, stream>>>(x, cb, r, rbf, cbbf, cbsq, hist, lbins);

    for (int q = 0; q < QSTAGE; ++q) {
        const size_t cboff = (size_t)q * CCODES * DDIM;
        gemm_dist_kernel<<<dim3(128, 4), 256, 0, stream>>>(
            rbf, cbbf + cboff, cbsq + q * CCODES, cand);
        refine_kernel<<<4096, 256, 0, stream>>>(
            r, rbf, cb + cboff, cbsq + q * CCODES, cand,
            out + OUT_IDX_OFF, hist + q * CCODES, lbins,
            q, (q < QSTAGE - 1) ? 1 : 0);
    }

    final_kernel<<<8193, 256, 0, stream>>>(x, r, out, hist, lbins,
                                           out + OUT_SCAL_OFF);
}